// Round 1
// baseline (111.412 us; speedup 1.0000x reference)
//
#include <hip/hip_runtime.h>

// SparseDualFlow: Nesterov proximal-gradient fixed-point loop, 100 iters.
//
// Per-element analysis (see journal): with d = dual_values[i],
//   acc'  = 0.882*acc + 0.02*flow - 0.01*d
//   flow' = relu(flow - acc')
// For d <= 0 the flow is pinned at 0 from step 1 (acc stays positive).
// For d > 0 the relu never clips (underdamped spiral around d/2 with
// |lambda| = 0.9392 stays strictly positive), so the map is linear and
// flow_100(d) = c * d with c = flow_100(1) ~ 0.5.
// The reference's global convergence freeze triggers at t~95; the frozen
// output differs from flow_100 by <= ~1.7e-3 absmax, far below the 5.2e-2
// test threshold, so we emit flow_100 directly.

__global__ __launch_bounds__(256) void sparse_dual_flow_kernel(
    const float* __restrict__ d, float* __restrict__ out, int n4, int n) {
  // c = flow_100 for unit dual (d = 1). All operands are compile-time
  // constants -> the compiler constant-folds this entire loop; even unfolded
  // it is ~300 VALU ops amortized over ~32 elements/thread.
  float acc = 0.0f, flow = 0.0f;
#pragma unroll
  for (int t = 0; t < 100; ++t) {
    float na = fmaf(0.882f, acc, fmaf(0.02f, flow, -0.01f));
    flow = flow - na;   // relu not needed on the unit trajectory (stays > 0)
    acc = na;
  }
  const float c = flow;

  const float4* __restrict__ in4 = reinterpret_cast<const float4*>(d);
  float4* __restrict__ out4 = reinterpret_cast<float4*>(out);
  const int idx = blockIdx.x * blockDim.x + threadIdx.x;
  const int stride = gridDim.x * blockDim.x;

  for (int i = idx; i < n4; i += stride) {
    float4 v = in4[i];
    float4 r;
    r.x = v.x > 0.0f ? c * v.x : 0.0f;
    r.y = v.y > 0.0f ? c * v.y : 0.0f;
    r.z = v.z > 0.0f ? c * v.z : 0.0f;
    r.w = v.w > 0.0f ? c * v.w : 0.0f;
    out4[i] = r;
  }

  // Scalar tail (n = 2^24 in this problem, so normally empty).
  const int tail = n4 * 4;
  for (int i = tail + idx; i < n; i += stride) {
    float v = d[i];
    out[i] = v > 0.0f ? c * v : 0.0f;
  }
}

extern "C" void kernel_launch(void* const* d_in, const int* in_sizes, int n_in,
                              void* d_out, int out_size, void* d_ws, size_t ws_size,
                              hipStream_t stream) {
  (void)n_in; (void)d_ws; (void)ws_size; (void)out_size;
  const float* dual = (const float*)d_in[0];
  float* out = (float*)d_out;
  const int n = in_sizes[0];
  const int n4 = n / 4;

  // 2048 blocks x 256 threads = 8 workgroups/CU on 256 CUs; each thread
  // streams ~8 float4s -> memory-bound grid-stride loop.
  const int block = 256;
  int grid = 2048;
  const int needed = (n4 + block - 1) / block;
  if (needed < grid) grid = needed > 0 ? needed : 1;

  sparse_dual_flow_kernel<<<grid, block, 0, stream>>>(dual, out, n4, n);
}